// Round 1
// baseline (854.084 us; speedup 1.0000x reference)
//
#include <hip/hip_runtime.h>
#include <cstdint>
#include <cstddef>

typedef __bf16 bf16;
typedef __bf16 bf16x8 __attribute__((ext_vector_type(8)));
typedef __bf16 bf16x4 __attribute__((ext_vector_type(4)));
typedef float f32x4 __attribute__((ext_vector_type(4)));

#define D_MODEL 2048
#define NH 16
#define HD 128
#define LQ 2048
#define LT 4096

__device__ __forceinline__ void gload16(const void* g, void* l) {
  __builtin_amdgcn_global_load_lds((const __attribute__((address_space(1))) void*)g,
                                   (__attribute__((address_space(3))) void*)l, 16, 0, 0);
}

// ---------------- elementwise fp32 -> bf16 ----------------
__global__ __launch_bounds__(256) void conv_bf16(const float* __restrict__ s, bf16* __restrict__ d, int n) {
  int i = (blockIdx.x * 256 + threadIdx.x) * 4;
  if (i >= n) return;
  float4 v = *(const float4*)(s + i);
  bf16x4 o = { (bf16)v.x, (bf16)v.y, (bf16)v.z, (bf16)v.w };
  *(bf16x4*)(d + i) = o;
}

// ---------------- copy past K/V into cache (fp32 out, optional bf16) ----------------
// src layout [BH][2048][128]; dst layout [BH][4096][128] rows 0..2047
__global__ __launch_bounds__(256) void copy_past(const float* __restrict__ src, float* __restrict__ dstf,
                                                 bf16* __restrict__ dstb) {
  int i = (blockIdx.x * 256 + threadIdx.x) * 4;
  int bh = i >> 18;          // / (2048*128)
  int rem = i & 262143;
  size_t o = ((size_t)bh << 19) + rem;   // * (4096*128)
  float4 v = *(const float4*)(src + i);
  *(float4*)(dstf + o) = v;
  if (dstb) {
    bf16x4 ob = { (bf16)v.x, (bf16)v.y, (bf16)v.z, (bf16)v.w };
    *(bf16x4*)(dstb + o) = ob;
  }
}

// ---------------- shared 128x128 bf16 GEMM mainloop (C = A * B^T), K = 2048 ----------------
__device__ __forceinline__ void gemm128_mainloop(const bf16* __restrict__ A, const bf16* __restrict__ B,
                                                 int m0, int n0, bf16* As, bf16* Bs, f32x4 (&acc)[4][4]) {
  const int tid = threadIdx.x, lane = tid & 63, w = tid >> 6;
  const int srow = w * 8 + (lane >> 3), scol = (lane & 7) * 8;
  const int wm = (w >> 1) * 64, wn = (w & 1) * 64, fr = lane & 15, fg = lane >> 4;
  for (int k0 = 0; k0 < 2048; k0 += 64) {
#pragma unroll
    for (int i = 0; i < 4; i++) {
      gload16(A + (size_t)(m0 + i * 32 + srow) * 2048 + k0 + scol, As + (i * 32 + w * 8) * 64);
      gload16(B + (size_t)(n0 + i * 32 + srow) * 2048 + k0 + scol, Bs + (i * 32 + w * 8) * 64);
    }
    __syncthreads();
#pragma unroll
    for (int kk = 0; kk < 2; kk++) {
      bf16x8 af[4], bfr[4];
#pragma unroll
      for (int mi = 0; mi < 4; mi++) af[mi] = *(const bf16x8*)(As + (wm + mi * 16 + fr) * 64 + kk * 32 + fg * 8);
#pragma unroll
      for (int ni = 0; ni < 4; ni++) bfr[ni] = *(const bf16x8*)(Bs + (wn + ni * 16 + fr) * 64 + kk * 32 + fg * 8);
#pragma unroll
      for (int mi = 0; mi < 4; mi++)
#pragma unroll
        for (int ni = 0; ni < 4; ni++)
          acc[mi][ni] = __builtin_amdgcn_mfma_f32_16x16x32_bf16(af[mi], bfr[ni], acc[mi][ni], 0, 0, 0);
    }
    __syncthreads();
  }
}

// ---------------- QKV projection; z = 0:Q  1:K  2:V ----------------
__global__ __launch_bounds__(256) void qkv_gemm(const bf16* __restrict__ xb, const bf16* __restrict__ wb,
    const float* __restrict__ bq, const float* __restrict__ bk, const float* __restrict__ bv,
    bf16* __restrict__ qb, float* __restrict__ kout, float* __restrict__ vout, bf16* __restrict__ kbf) {
  __shared__ alignas(16) bf16 As[128 * 64];
  __shared__ alignas(16) bf16 Bs[128 * 64];
  f32x4 acc[4][4];
#pragma unroll
  for (int a = 0; a < 4; a++)
#pragma unroll
    for (int b = 0; b < 4; b++) acc[a][b] = (f32x4){0.f, 0.f, 0.f, 0.f};
  const int z = blockIdx.z;
  const int m0 = blockIdx.y * 128, n0 = blockIdx.x * 128;
  gemm128_mainloop(xb, wb + (size_t)z * 4194304, m0, n0, As, Bs, acc);
  const int lane = threadIdx.x & 63, w = threadIdx.x >> 6;
  const int wm = (w >> 1) * 64, wn = (w & 1) * 64, fr = lane & 15, fg = lane >> 4;
  const float* bias = (z == 0) ? bq : (z == 1 ? bk : bv);
#pragma unroll
  for (int ni = 0; ni < 4; ni++) {
    int col = n0 + wn + ni * 16 + fr;
    float bi = bias[col];
#pragma unroll
    for (int mi = 0; mi < 4; mi++) {
#pragma unroll
      for (int r = 0; r < 4; r++) {
        int row = m0 + wm + mi * 16 + fg * 4 + r;
        float v = acc[mi][ni][r] + bi;
        if (z == 0) {
          qb[(size_t)row * 2048 + col] = (bf16)(v * 0.088388347648318447f);  // fold 1/sqrt(128)
        } else {
          size_t co = (((size_t)(row >> 11) * 16 + (col >> 7)) * 4096 + 2048 + (row & 2047)) * 128 + (col & 127);
          if (z == 1) { kout[co] = v; kbf[co] = (bf16)v; }
          else        { vout[co] = v; }
        }
      }
    }
  }
}

// ---------------- V cache -> transposed bf16  [BH][128][4096] ----------------
__global__ __launch_bounds__(256) void build_vt(const float* __restrict__ vsrc, bf16* __restrict__ vtb) {
  __shared__ float tile[64][65];
  const int tid = threadIdx.x;
  const int bh = blockIdx.z;
  const int t0 = blockIdx.x * 64, d0 = blockIdx.y * 64;
  const float* src = vsrc + ((size_t)bh * LT + t0) * HD + d0;
#pragma unroll
  for (int i = 0; i < 4; i++) {
    int idx = i * 256 + tid;
    int rr = idx >> 4, c4 = (idx & 15) * 4;
    float4 v = *(const float4*)(src + rr * HD + c4);
    tile[rr][c4 + 0] = v.x; tile[rr][c4 + 1] = v.y; tile[rr][c4 + 2] = v.z; tile[rr][c4 + 3] = v.w;
  }
  __syncthreads();
  bf16* dst = vtb + (size_t)bh * HD * LT + (size_t)d0 * LT + t0;
#pragma unroll
  for (int i = 0; i < 4; i++) {
    int idx = i * 256 + tid;
    int dr = idx >> 4, c4 = (idx & 15) * 4;
    bf16x4 o = { (bf16)tile[c4 + 0][dr], (bf16)tile[c4 + 1][dr],
                 (bf16)tile[c4 + 2][dr], (bf16)tile[c4 + 3][dr] };
    *(bf16x4*)(dst + (size_t)dr * LT + c4) = o;
  }
}

// ---------------- flash attention: 8 waves x 16 q-rows, KVBLK=64 ----------------
__global__ __launch_bounds__(512) void attn(const bf16* __restrict__ qb, const bf16* __restrict__ kb,
                                            const bf16* __restrict__ vtb, bf16* __restrict__ ctxb) {
  __shared__ alignas(16) bf16 kbuf[64 * 128];    // [key][d]
  __shared__ alignas(16) bf16 vtbuf[128 * 64];   // [d][key]
  __shared__ alignas(16) bf16 pbuf[8][16 * 64];  // per-wave [q][key]
  const int tid = threadIdx.x, lane = tid & 63, w = tid >> 6;
  const int fr = lane & 15, fg = lane >> 4;
  const int bh = blockIdx.y, b = bh >> 4;
  const int q0 = blockIdx.x * 128;
  const bf16* qrow = qb + (size_t)(b * LQ + q0 + w * 16 + fr) * D_MODEL + (bh & 15) * HD;
  bf16x8 aq[4];
#pragma unroll
  for (int c = 0; c < 4; c++) aq[c] = *(const bf16x8*)(qrow + c * 32 + fg * 8);
  const bf16* Kb = kb + (size_t)bh * LT * HD;
  const bf16* Vt = vtb + (size_t)bh * HD * LT;
  float m_[4], s_[4];
  f32x4 ctx[8];
#pragma unroll
  for (int r = 0; r < 4; r++) { m_[r] = -__builtin_inff(); s_[r] = 0.f; }
#pragma unroll
  for (int d = 0; d < 8; d++) ctx[d] = (f32x4){0.f, 0.f, 0.f, 0.f};

  const int ksrow = tid >> 4, kscol = (tid & 15) * 8;
  const int vsrow = tid >> 3, vscol = (tid & 7) * 8;

  for (int k0 = 0; k0 < LT; k0 += 64) {
#pragma unroll
    for (int j = 0; j < 2; j++) {
      gload16(Kb + (size_t)(k0 + j * 32 + ksrow) * HD + kscol, kbuf + (j * 32 + w * 4) * HD);
      gload16(Vt + (size_t)(j * 64 + vsrow) * LT + k0 + vscol, vtbuf + (j * 64 + w * 8) * 64);
    }
    __syncthreads();
    // S = Q * K^T (pre-scaled Q): 4 column groups of 16 keys
    f32x4 sS[4];
#pragma unroll
    for (int n = 0; n < 4; n++) {
      sS[n] = (f32x4){0.f, 0.f, 0.f, 0.f};
#pragma unroll
      for (int c = 0; c < 4; c++) {
        bf16x8 kf = *(const bf16x8*)(kbuf + (n * 16 + fr) * HD + c * 32 + fg * 8);
        sS[n] = __builtin_amdgcn_mfma_f32_16x16x32_bf16(aq[c], kf, sS[n], 0, 0, 0);
      }
    }
    // online softmax; row layout q = fg*4 + r, cols spread over 16-lane groups
    float al[4], rs[4];
#pragma unroll
    for (int r = 0; r < 4; r++) {
      float t = fmaxf(fmaxf(sS[0][r], sS[1][r]), fmaxf(sS[2][r], sS[3][r]));
#pragma unroll
      for (int mk = 1; mk <= 8; mk <<= 1) t = fmaxf(t, __shfl_xor(t, mk));
      float mn = fmaxf(m_[r], t);
      al[r] = __expf(m_[r] - mn);
      m_[r] = mn;
      float rsum = 0.f;
#pragma unroll
      for (int n = 0; n < 4; n++) {
        float pe = __expf(sS[n][r] - mn);
        sS[n][r] = pe;
        rsum += pe;
      }
      rs[r] = rsum;
    }
#pragma unroll
    for (int r = 0; r < 4; r++) {
#pragma unroll
      for (int mk = 1; mk <= 8; mk <<= 1) rs[r] += __shfl_xor(rs[r], mk);
      s_[r] = s_[r] * al[r] + rs[r];
    }
#pragma unroll
    for (int d = 0; d < 8; d++)
#pragma unroll
      for (int r = 0; r < 4; r++) ctx[d][r] *= al[r];
    // P -> per-wave LDS (to reach A-fragment layout)
    bf16* pw = &pbuf[w][0];
#pragma unroll
    for (int n = 0; n < 4; n++)
#pragma unroll
      for (int r = 0; r < 4; r++)
        pw[(fg * 4 + r) * 64 + n * 16 + fr] = (bf16)sS[n][r];
    __syncthreads();
    bf16x8 pf0 = *(const bf16x8*)(pw + fr * 64 + fg * 8);
    bf16x8 pf1 = *(const bf16x8*)(pw + fr * 64 + 32 + fg * 8);
#pragma unroll
    for (int d = 0; d < 8; d++) {
      bf16x8 v0 = *(const bf16x8*)(vtbuf + (d * 16 + fr) * 64 + fg * 8);
      ctx[d] = __builtin_amdgcn_mfma_f32_16x16x32_bf16(pf0, v0, ctx[d], 0, 0, 0);
      bf16x8 v1 = *(const bf16x8*)(vtbuf + (d * 16 + fr) * 64 + 32 + fg * 8);
      ctx[d] = __builtin_amdgcn_mfma_f32_16x16x32_bf16(pf1, v1, ctx[d], 0, 0, 0);
    }
    __syncthreads();
  }
  float inv[4];
#pragma unroll
  for (int r = 0; r < 4; r++) inv[r] = 1.f / s_[r];
  bf16* crow = ctxb + (size_t)(b * LQ + q0 + w * 16 + fg * 4) * D_MODEL + (bh & 15) * HD + fr;
#pragma unroll
  for (int r = 0; r < 4; r++)
#pragma unroll
    for (int d = 0; d < 8; d++)
      crow[(size_t)r * D_MODEL + d * 16] = (bf16)(ctx[d][r] * inv[r]);
}

// ---------------- output projection ----------------
__global__ __launch_bounds__(256) void out_gemm(const bf16* __restrict__ cb, const bf16* __restrict__ wo,
                                                const float* __restrict__ bo, float* __restrict__ out) {
  __shared__ alignas(16) bf16 As[128 * 64];
  __shared__ alignas(16) bf16 Bs[128 * 64];
  f32x4 acc[4][4];
#pragma unroll
  for (int a = 0; a < 4; a++)
#pragma unroll
    for (int b = 0; b < 4; b++) acc[a][b] = (f32x4){0.f, 0.f, 0.f, 0.f};
  const int m0 = blockIdx.y * 128, n0 = blockIdx.x * 128;
  gemm128_mainloop(cb, wo, m0, n0, As, Bs, acc);
  const int lane = threadIdx.x & 63, w = threadIdx.x >> 6;
  const int wm = (w >> 1) * 64, wn = (w & 1) * 64, fr = lane & 15, fg = lane >> 4;
#pragma unroll
  for (int ni = 0; ni < 4; ni++) {
    int col = n0 + wn + ni * 16 + fr;
    float bi = bo[col];
#pragma unroll
    for (int mi = 0; mi < 4; mi++)
#pragma unroll
      for (int r = 0; r < 4; r++) {
        int row = m0 + wm + mi * 16 + fg * 4 + r;
        out[(size_t)row * 2048 + col] = acc[mi][ni][r] + bi;
      }
  }
}

extern "C" void kernel_launch(void* const* d_in, const int* in_sizes, int n_in,
                              void* d_out, int out_size, void* d_ws, size_t ws_size,
                              hipStream_t stream) {
  const float* x  = (const float*)d_in[0];
  const float* pk = (const float*)d_in[1];
  const float* pv = (const float*)d_in[2];
  const float* Wq = (const float*)d_in[3];
  const float* bq = (const float*)d_in[4];
  const float* Wk = (const float*)d_in[5];
  const float* bk = (const float*)d_in[6];
  const float* Wv = (const float*)d_in[7];
  const float* bv = (const float*)d_in[8];
  const float* Wo = (const float*)d_in[9];
  const float* bo = (const float*)d_in[10];

  float* out  = (float*)d_out;
  float* kout = out + 8388608;   // B*L*D
  float* vout = out + 25165824;

  char* p = (char*)d_ws;
  bf16* xb  = (bf16*)p;                   // 16 MiB, reused as ctxb after QKV gemm
  bf16* wb  = (bf16*)(p + 16777216);      // 32 MiB: Wq,Wk,Wv,Wo bf16
  bf16* qb  = (bf16*)(p + 50331648);      // 16 MiB (pre-scaled Q)
  bf16* kbf = (bf16*)(p + 67108864);      // 32 MiB K cache bf16 [BH][4096][128]
  bf16* vtb = (bf16*)(p + 100663296);     // 32 MiB V^T cache bf16 [BH][128][4096]
  bf16* ctxb = xb;

  conv_bf16<<<8192, 256, 0, stream>>>(x, xb, 8388608);
  conv_bf16<<<4096, 256, 0, stream>>>(Wq, wb,            4194304);
  conv_bf16<<<4096, 256, 0, stream>>>(Wk, wb + 4194304,  4194304);
  conv_bf16<<<4096, 256, 0, stream>>>(Wv, wb + 8388608,  4194304);
  conv_bf16<<<4096, 256, 0, stream>>>(Wo, wb + 12582912, 4194304);
  copy_past<<<8192, 256, 0, stream>>>(pk, kout, kbf);
  copy_past<<<8192, 256, 0, stream>>>(pv, vout, nullptr);

  qkv_gemm<<<dim3(16, 32, 3), 256, 0, stream>>>(xb, wb, bq, bk, bv, qb, kout, vout, kbf);
  build_vt<<<dim3(64, 2, 32), 256, 0, stream>>>(vout, vtb);
  attn<<<dim3(16, 32), 512, 0, stream>>>(qb, kbf, vtb, ctxb);
  out_gemm<<<dim3(16, 32), 256, 0, stream>>>(ctxb, wb + 12582912, bo, out);
}

// Round 2
// 608.946 us; speedup vs baseline: 1.4026x; 1.4026x over previous
//
#include <hip/hip_runtime.h>
#include <cstdint>
#include <cstddef>

typedef __bf16 bf16;
typedef __bf16 bf16x8 __attribute__((ext_vector_type(8)));
typedef __bf16 bf16x4 __attribute__((ext_vector_type(4)));
typedef float f32x4 __attribute__((ext_vector_type(4)));

#define D_MODEL 2048
#define NH 16
#define HD 128
#define LQ 2048
#define LT 4096

__device__ __forceinline__ void gload16(const void* g, void* l) {
  __builtin_amdgcn_global_load_lds((const __attribute__((address_space(1))) void*)g,
                                   (__attribute__((address_space(3))) void*)l, 16, 0, 0);
}

// ---------------- elementwise fp32 -> bf16 ----------------
__global__ __launch_bounds__(256) void conv_bf16(const float* __restrict__ s, bf16* __restrict__ d, int n) {
  int i = (blockIdx.x * 256 + threadIdx.x) * 4;
  if (i >= n) return;
  float4 v = *(const float4*)(s + i);
  bf16x4 o = { (bf16)v.x, (bf16)v.y, (bf16)v.z, (bf16)v.w };
  *(bf16x4*)(d + i) = o;
}

// ---------------- copy past K/V into cache (fp32 out, optional bf16) ----------------
// src layout [BH][2048][128]; dst layout [BH][4096][128] rows 0..2047
__global__ __launch_bounds__(256) void copy_past(const float* __restrict__ src, float* __restrict__ dstf,
                                                 bf16* __restrict__ dstb) {
  int i = (blockIdx.x * 256 + threadIdx.x) * 4;
  int bh = i >> 18;          // / (2048*128)
  int rem = i & 262143;
  size_t o = ((size_t)bh << 19) + rem;   // * (4096*128)
  float4 v = *(const float4*)(src + i);
  *(float4*)(dstf + o) = v;
  if (dstb) {
    bf16x4 ob = { (bf16)v.x, (bf16)v.y, (bf16)v.z, (bf16)v.w };
    *(bf16x4*)(dstb + o) = ob;
  }
}

// ---------------- shared 128x128 bf16 GEMM mainloop (C = A * B^T), K = 2048 ----------------
__device__ __forceinline__ void gemm128_mainloop(const bf16* __restrict__ A, const bf16* __restrict__ B,
                                                 int m0, int n0, bf16* As, bf16* Bs, f32x4 (&acc)[4][4]) {
  const int tid = threadIdx.x, lane = tid & 63, w = tid >> 6;
  const int srow = w * 8 + (lane >> 3), scol = (lane & 7) * 8;
  const int wm = (w >> 1) * 64, wn = (w & 1) * 64, fr = lane & 15, fg = lane >> 4;
  for (int k0 = 0; k0 < 2048; k0 += 64) {
#pragma unroll
    for (int i = 0; i < 4; i++) {
      gload16(A + (size_t)(m0 + i * 32 + srow) * 2048 + k0 + scol, As + (i * 32 + w * 8) * 64);
      gload16(B + (size_t)(n0 + i * 32 + srow) * 2048 + k0 + scol, Bs + (i * 32 + w * 8) * 64);
    }
    __syncthreads();
#pragma unroll
    for (int kk = 0; kk < 2; kk++) {
      bf16x8 af[4], bfr[4];
#pragma unroll
      for (int mi = 0; mi < 4; mi++) af[mi] = *(const bf16x8*)(As + (wm + mi * 16 + fr) * 64 + kk * 32 + fg * 8);
#pragma unroll
      for (int ni = 0; ni < 4; ni++) bfr[ni] = *(const bf16x8*)(Bs + (wn + ni * 16 + fr) * 64 + kk * 32 + fg * 8);
#pragma unroll
      for (int mi = 0; mi < 4; mi++)
#pragma unroll
        for (int ni = 0; ni < 4; ni++)
          acc[mi][ni] = __builtin_amdgcn_mfma_f32_16x16x32_bf16(af[mi], bfr[ni], acc[mi][ni], 0, 0, 0);
    }
    __syncthreads();
  }
}

// ---------------- QKV projection; z = 0:Q  1:K  2:V ----------------
__global__ __launch_bounds__(256) void qkv_gemm(const bf16* __restrict__ xb, const bf16* __restrict__ wb,
    const float* __restrict__ bq, const float* __restrict__ bk, const float* __restrict__ bv,
    bf16* __restrict__ qb, float* __restrict__ kout, float* __restrict__ vout, bf16* __restrict__ kbf) {
  __shared__ alignas(16) bf16 As[128 * 64];
  __shared__ alignas(16) bf16 Bs[128 * 64];
  f32x4 acc[4][4];
#pragma unroll
  for (int a = 0; a < 4; a++)
#pragma unroll
    for (int b = 0; b < 4; b++) acc[a][b] = (f32x4){0.f, 0.f, 0.f, 0.f};
  const int z = blockIdx.z;
  const int m0 = blockIdx.y * 128, n0 = blockIdx.x * 128;
  gemm128_mainloop(xb, wb + (size_t)z * 4194304, m0, n0, As, Bs, acc);
  const int lane = threadIdx.x & 63, w = threadIdx.x >> 6;
  const int wm = (w >> 1) * 64, wn = (w & 1) * 64, fr = lane & 15, fg = lane >> 4;
  const float* bias = (z == 0) ? bq : (z == 1 ? bk : bv);
#pragma unroll
  for (int ni = 0; ni < 4; ni++) {
    int col = n0 + wn + ni * 16 + fr;
    float bi = bias[col];
#pragma unroll
    for (int mi = 0; mi < 4; mi++) {
#pragma unroll
      for (int r = 0; r < 4; r++) {
        int row = m0 + wm + mi * 16 + fg * 4 + r;
        float v = acc[mi][ni][r] + bi;
        if (z == 0) {
          qb[(size_t)row * 2048 + col] = (bf16)(v * 0.088388347648318447f);  // fold 1/sqrt(128)
        } else {
          size_t co = (((size_t)(row >> 11) * 16 + (col >> 7)) * 4096 + 2048 + (row & 2047)) * 128 + (col & 127);
          if (z == 1) { kout[co] = v; kbf[co] = (bf16)v; }
          else        { vout[co] = v; }
        }
      }
    }
  }
}

// ---------------- V cache -> transposed bf16  [BH][128][4096] ----------------
__global__ __launch_bounds__(256) void build_vt(const float* __restrict__ vsrc, bf16* __restrict__ vtb) {
  __shared__ float tile[64][65];
  const int tid = threadIdx.x;
  const int bh = blockIdx.z;
  const int t0 = blockIdx.x * 64, d0 = blockIdx.y * 64;
  const float* src = vsrc + ((size_t)bh * LT + t0) * HD + d0;
#pragma unroll
  for (int i = 0; i < 4; i++) {
    int idx = i * 256 + tid;
    int rr = idx >> 4, c4 = (idx & 15) * 4;
    float4 v = *(const float4*)(src + rr * HD + c4);
    tile[rr][c4 + 0] = v.x; tile[rr][c4 + 1] = v.y; tile[rr][c4 + 2] = v.z; tile[rr][c4 + 3] = v.w;
  }
  __syncthreads();
  bf16* dst = vtb + (size_t)bh * HD * LT + (size_t)d0 * LT + t0;
#pragma unroll
  for (int i = 0; i < 4; i++) {
    int idx = i * 256 + tid;
    int dr = idx >> 4, c4 = (idx & 15) * 4;
    bf16x4 o = { (bf16)tile[c4 + 0][dr], (bf16)tile[c4 + 1][dr],
                 (bf16)tile[c4 + 2][dr], (bf16)tile[c4 + 3][dr] };
    *(bf16x4*)(dst + (size_t)dr * LT + c4) = o;
  }
}

// ---------------- flash attention: 8 waves x 16 q-rows, KVBLK=64 ----------------
// LDS bank-conflict fix (T2 / G4):
//   kbuf rows are 256B, vtbuf rows are 128B. XOR-swizzle byte ^= ((row&7)<<4),
//   applied as: inverse-permuted per-lane GLOBAL source col (global_load_lds
//   dest must stay linear, rule #21) + same XOR on ds_read addresses.
//   pbuf is reg-written, so pad rows to 72 elements (144B) instead.
__global__ __launch_bounds__(512) void attn(const bf16* __restrict__ qb, const bf16* __restrict__ kb,
                                            const bf16* __restrict__ vtb, bf16* __restrict__ ctxb) {
  __shared__ alignas(16) bf16 kbuf[64 * 128];    // [key][d], swizzled
  __shared__ alignas(16) bf16 vtbuf[128 * 64];   // [d][key], swizzled
  __shared__ alignas(16) bf16 pbuf[8][16 * 72];  // per-wave [q][key], padded rows
  const int tid = threadIdx.x, lane = tid & 63, w = tid >> 6;
  const int fr = lane & 15, fg = lane >> 4;
  const int bh = blockIdx.y, b = bh >> 4;
  const int q0 = blockIdx.x * 128;
  const bf16* qrow = qb + (size_t)(b * LQ + q0 + w * 16 + fr) * D_MODEL + (bh & 15) * HD;
  bf16x8 aq[4];
#pragma unroll
  for (int c = 0; c < 4; c++) aq[c] = *(const bf16x8*)(qrow + c * 32 + fg * 8);
  const bf16* Kb = kb + (size_t)bh * LT * HD;
  const bf16* Vt = vtb + (size_t)bh * HD * LT;
  float m_[4], s_[4];
  f32x4 ctx[8];
#pragma unroll
  for (int r = 0; r < 4; r++) { m_[r] = -__builtin_inff(); s_[r] = 0.f; }
#pragma unroll
  for (int d = 0; d < 8; d++) ctx[d] = (f32x4){0.f, 0.f, 0.f, 0.f};

  // staging geometry: wave w stages K rows {j*32 + w*4 + (lane>>4)}, 16B chunk (lane&15)
  //                   and Vt rows {j*64 + w*8 + (lane>>3)}, 16B chunk (lane&7)
  const int krow_lo = w * 4 + (lane >> 4);            // K row within 32-row group (mod 8 valid: w*4+.. <= 31)
  const int kscol = (((lane & 15) ^ (krow_lo & 7)) * 8);   // inverse-swizzled source col (elements)
  const int vrow_lo = (lane >> 3) & 7;
  const int vscol = (((lane & 7) ^ vrow_lo) * 8);

  for (int k0 = 0; k0 < LT; k0 += 64) {
#pragma unroll
    for (int j = 0; j < 2; j++) {
      gload16(Kb + (size_t)(k0 + j * 32 + krow_lo) * HD + kscol, kbuf + (j * 32 + w * 4) * HD);
      gload16(Vt + (size_t)(j * 64 + w * 8 + (lane >> 3)) * LT + k0 + vscol, vtbuf + (j * 64 + w * 8) * 64);
    }
    __syncthreads();
    // S = Q * K^T (pre-scaled Q): 4 column groups of 16 keys
    f32x4 sS[4];
#pragma unroll
    for (int n = 0; n < 4; n++) {
      sS[n] = (f32x4){0.f, 0.f, 0.f, 0.f};
#pragma unroll
      for (int c = 0; c < 4; c++) {
        bf16x8 kf = *(const bf16x8*)(kbuf + (n * 16 + fr) * HD + (((c * 4 + fg) ^ (fr & 7)) * 8));
        sS[n] = __builtin_amdgcn_mfma_f32_16x16x32_bf16(aq[c], kf, sS[n], 0, 0, 0);
      }
    }
    // online softmax; row layout q = fg*4 + r, cols spread over 16-lane groups
    float al[4], rs[4];
#pragma unroll
    for (int r = 0; r < 4; r++) {
      float t = fmaxf(fmaxf(sS[0][r], sS[1][r]), fmaxf(sS[2][r], sS[3][r]));
#pragma unroll
      for (int mk = 1; mk <= 8; mk <<= 1) t = fmaxf(t, __shfl_xor(t, mk));
      float mn = fmaxf(m_[r], t);
      al[r] = __expf(m_[r] - mn);
      m_[r] = mn;
      float rsum = 0.f;
#pragma unroll
      for (int n = 0; n < 4; n++) {
        float pe = __expf(sS[n][r] - mn);
        sS[n][r] = pe;
        rsum += pe;
      }
      rs[r] = rsum;
    }
#pragma unroll
    for (int r = 0; r < 4; r++) {
#pragma unroll
      for (int mk = 1; mk <= 8; mk <<= 1) rs[r] += __shfl_xor(rs[r], mk);
      s_[r] = s_[r] * al[r] + rs[r];
    }
#pragma unroll
    for (int d = 0; d < 8; d++)
#pragma unroll
      for (int r = 0; r < 4; r++) ctx[d][r] *= al[r];
    // P -> per-wave LDS (to reach A-fragment layout); rows padded to 72
    bf16* pw = &pbuf[w][0];
#pragma unroll
    for (int n = 0; n < 4; n++)
#pragma unroll
      for (int r = 0; r < 4; r++)
        pw[(fg * 4 + r) * 72 + n * 16 + fr] = (bf16)sS[n][r];
    __syncthreads();
    bf16x8 pf0 = *(const bf16x8*)(pw + fr * 72 + fg * 8);
    bf16x8 pf1 = *(const bf16x8*)(pw + fr * 72 + 32 + fg * 8);
#pragma unroll
    for (int d = 0; d < 8; d++) {
      bf16x8 v0 = *(const bf16x8*)(vtbuf + (d * 16 + fr) * 64 + ((fg ^ (fr & 7)) * 8));
      ctx[d] = __builtin_amdgcn_mfma_f32_16x16x32_bf16(pf0, v0, ctx[d], 0, 0, 0);
      bf16x8 v1 = *(const bf16x8*)(vtbuf + (d * 16 + fr) * 64 + (((4 + fg) ^ (fr & 7)) * 8));
      ctx[d] = __builtin_amdgcn_mfma_f32_16x16x32_bf16(pf1, v1, ctx[d], 0, 0, 0);
    }
    __syncthreads();
  }
  float inv[4];
#pragma unroll
  for (int r = 0; r < 4; r++) inv[r] = 1.f / s_[r];
  bf16* crow = ctxb + (size_t)(b * LQ + q0 + w * 16 + fg * 4) * D_MODEL + (bh & 15) * HD + fr;
#pragma unroll
  for (int r = 0; r < 4; r++)
#pragma unroll
    for (int d = 0; d < 8; d++)
      crow[(size_t)r * D_MODEL + d * 16] = (bf16)(ctx[d][r] * inv[r]);
}

// ---------------- output projection ----------------
__global__ __launch_bounds__(256) void out_gemm(const bf16* __restrict__ cb, const bf16* __restrict__ wo,
                                                const float* __restrict__ bo, float* __restrict__ out) {
  __shared__ alignas(16) bf16 As[128 * 64];
  __shared__ alignas(16) bf16 Bs[128 * 64];
  f32x4 acc[4][4];
#pragma unroll
  for (int a = 0; a < 4; a++)
#pragma unroll
    for (int b = 0; b < 4; b++) acc[a][b] = (f32x4){0.f, 0.f, 0.f, 0.f};
  const int m0 = blockIdx.y * 128, n0 = blockIdx.x * 128;
  gemm128_mainloop(cb, wo, m0, n0, As, Bs, acc);
  const int lane = threadIdx.x & 63, w = threadIdx.x >> 6;
  const int wm = (w >> 1) * 64, wn = (w & 1) * 64, fr = lane & 15, fg = lane >> 4;
#pragma unroll
  for (int ni = 0; ni < 4; ni++) {
    int col = n0 + wn + ni * 16 + fr;
    float bi = bo[col];
#pragma unroll
    for (int mi = 0; mi < 4; mi++)
#pragma unroll
      for (int r = 0; r < 4; r++) {
        int row = m0 + wm + mi * 16 + fg * 4 + r;
        out[(size_t)row * 2048 + col] = acc[mi][ni][r] + bi;
      }
  }
}

extern "C" void kernel_launch(void* const* d_in, const int* in_sizes, int n_in,
                              void* d_out, int out_size, void* d_ws, size_t ws_size,
                              hipStream_t stream) {
  const float* x  = (const float*)d_in[0];
  const float* pk = (const float*)d_in[1];
  const float* pv = (const float*)d_in[2];
  const float* Wq = (const float*)d_in[3];
  const float* bq = (const float*)d_in[4];
  const float* Wk = (const float*)d_in[5];
  const float* bk = (const float*)d_in[6];
  const float* Wv = (const float*)d_in[7];
  const float* bv = (const float*)d_in[8];
  const float* Wo = (const float*)d_in[9];
  const float* bo = (const float*)d_in[10];

  float* out  = (float*)d_out;
  float* kout = out + 8388608;   // B*L*D
  float* vout = out + 25165824;

  char* p = (char*)d_ws;
  bf16* xb  = (bf16*)p;                   // 16 MiB, reused as ctxb after QKV gemm
  bf16* wb  = (bf16*)(p + 16777216);      // 32 MiB: Wq,Wk,Wv,Wo bf16
  bf16* qb  = (bf16*)(p + 50331648);      // 16 MiB (pre-scaled Q)
  bf16* kbf = (bf16*)(p + 67108864);      // 32 MiB K cache bf16 [BH][4096][128]
  bf16* vtb = (bf16*)(p + 100663296);     // 32 MiB V^T cache bf16 [BH][128][4096]
  bf16* ctxb = xb;

  conv_bf16<<<8192, 256, 0, stream>>>(x, xb, 8388608);
  conv_bf16<<<4096, 256, 0, stream>>>(Wq, wb,            4194304);
  conv_bf16<<<4096, 256, 0, stream>>>(Wk, wb + 4194304,  4194304);
  conv_bf16<<<4096, 256, 0, stream>>>(Wv, wb + 8388608,  4194304);
  conv_bf16<<<4096, 256, 0, stream>>>(Wo, wb + 12582912, 4194304);
  copy_past<<<8192, 256, 0, stream>>>(pk, kout, kbf);
  copy_past<<<8192, 256, 0, stream>>>(pv, vout, nullptr);

  qkv_gemm<<<dim3(16, 32, 3), 256, 0, stream>>>(xb, wb, bq, bk, bv, qb, kout, vout, kbf);
  build_vt<<<dim3(64, 2, 32), 256, 0, stream>>>(vout, vtb);
  attn<<<dim3(16, 32), 512, 0, stream>>>(qb, kbf, vtb, ctxb);
  out_gemm<<<dim3(16, 32), 256, 0, stream>>>(ctxb, wb + 12582912, bo, out);
}

// Round 3
// 598.253 us; speedup vs baseline: 1.4276x; 1.0179x over previous
//
#include <hip/hip_runtime.h>
#include <cstdint>
#include <cstddef>

typedef __bf16 bf16;
typedef __bf16 bf16x8 __attribute__((ext_vector_type(8)));
typedef __bf16 bf16x4 __attribute__((ext_vector_type(4)));
typedef float f32x4 __attribute__((ext_vector_type(4)));

#define D_MODEL 2048
#define NH 16
#define HD 128
#define LQ 2048
#define LT 4096

__device__ __forceinline__ void gload16(const void* g, void* l) {
  __builtin_amdgcn_global_load_lds((const __attribute__((address_space(1))) void*)g,
                                   (__attribute__((address_space(3))) void*)l, 16, 0, 0);
}

// ---------------- elementwise fp32 -> bf16 ----------------
__global__ __launch_bounds__(256) void conv_bf16(const float* __restrict__ s, bf16* __restrict__ d, int n) {
  int i = (blockIdx.x * 256 + threadIdx.x) * 4;
  if (i >= n) return;
  float4 v = *(const float4*)(s + i);
  bf16x4 o = { (bf16)v.x, (bf16)v.y, (bf16)v.z, (bf16)v.w };
  *(bf16x4*)(d + i) = o;
}

// ---------------- copy past K/V into cache (fp32 out, optional bf16) ----------------
// src layout [BH][2048][128]; dst layout [BH][4096][128] rows 0..2047
__global__ __launch_bounds__(256) void copy_past(const float* __restrict__ src, float* __restrict__ dstf,
                                                 bf16* __restrict__ dstb) {
  int i = (blockIdx.x * 256 + threadIdx.x) * 4;
  int bh = i >> 18;          // / (2048*128)
  int rem = i & 262143;
  size_t o = ((size_t)bh << 19) + rem;   // * (4096*128)
  float4 v = *(const float4*)(src + i);
  *(float4*)(dstf + o) = v;
  if (dstb) {
    bf16x4 ob = { (bf16)v.x, (bf16)v.y, (bf16)v.z, (bf16)v.w };
    *(bf16x4*)(dstb + o) = ob;
  }
}

// ---------------- shared 128x128 bf16 GEMM mainloop (C = A * B^T), K = 2048 ----------------
__device__ __forceinline__ void gemm128_mainloop(const bf16* __restrict__ A, const bf16* __restrict__ B,
                                                 int m0, int n0, bf16* As, bf16* Bs, f32x4 (&acc)[4][4]) {
  const int tid = threadIdx.x, lane = tid & 63, w = tid >> 6;
  const int srow = w * 8 + (lane >> 3), scol = (lane & 7) * 8;
  const int wm = (w >> 1) * 64, wn = (w & 1) * 64, fr = lane & 15, fg = lane >> 4;
  for (int k0 = 0; k0 < 2048; k0 += 64) {
#pragma unroll
    for (int i = 0; i < 4; i++) {
      gload16(A + (size_t)(m0 + i * 32 + srow) * 2048 + k0 + scol, As + (i * 32 + w * 8) * 64);
      gload16(B + (size_t)(n0 + i * 32 + srow) * 2048 + k0 + scol, Bs + (i * 32 + w * 8) * 64);
    }
    __syncthreads();
#pragma unroll
    for (int kk = 0; kk < 2; kk++) {
      bf16x8 af[4], bfr[4];
#pragma unroll
      for (int mi = 0; mi < 4; mi++) af[mi] = *(const bf16x8*)(As + (wm + mi * 16 + fr) * 64 + kk * 32 + fg * 8);
#pragma unroll
      for (int ni = 0; ni < 4; ni++) bfr[ni] = *(const bf16x8*)(Bs + (wn + ni * 16 + fr) * 64 + kk * 32 + fg * 8);
#pragma unroll
      for (int mi = 0; mi < 4; mi++)
#pragma unroll
        for (int ni = 0; ni < 4; ni++)
          acc[mi][ni] = __builtin_amdgcn_mfma_f32_16x16x32_bf16(af[mi], bfr[ni], acc[mi][ni], 0, 0, 0);
    }
    __syncthreads();
  }
}

// ---------------- QKV projection; z = 0:Q  1:K  2:V ----------------
__global__ __launch_bounds__(256) void qkv_gemm(const bf16* __restrict__ xb, const bf16* __restrict__ wb,
    const float* __restrict__ bq, const float* __restrict__ bk, const float* __restrict__ bv,
    bf16* __restrict__ qb, float* __restrict__ kout, float* __restrict__ vout, bf16* __restrict__ kbf) {
  __shared__ alignas(16) bf16 As[128 * 64];
  __shared__ alignas(16) bf16 Bs[128 * 64];
  f32x4 acc[4][4];
#pragma unroll
  for (int a = 0; a < 4; a++)
#pragma unroll
    for (int b = 0; b < 4; b++) acc[a][b] = (f32x4){0.f, 0.f, 0.f, 0.f};
  const int z = blockIdx.z;
  const int m0 = blockIdx.y * 128, n0 = blockIdx.x * 128;
  gemm128_mainloop(xb, wb + (size_t)z * 4194304, m0, n0, As, Bs, acc);
  const int lane = threadIdx.x & 63, w = threadIdx.x >> 6;
  const int wm = (w >> 1) * 64, wn = (w & 1) * 64, fr = lane & 15, fg = lane >> 4;
  const float* bias = (z == 0) ? bq : (z == 1 ? bk : bv);
#pragma unroll
  for (int ni = 0; ni < 4; ni++) {
    int col = n0 + wn + ni * 16 + fr;
    float bi = bias[col];
#pragma unroll
    for (int mi = 0; mi < 4; mi++) {
#pragma unroll
      for (int r = 0; r < 4; r++) {
        int row = m0 + wm + mi * 16 + fg * 4 + r;
        float v = acc[mi][ni][r] + bi;
        if (z == 0) {
          // fold 1/sqrt(128) * log2(e) so attn can use v_exp_f32 (exp2) directly
          qb[(size_t)row * 2048 + col] = (bf16)(v * 0.12751744955867606f);
        } else {
          size_t co = (((size_t)(row >> 11) * 16 + (col >> 7)) * 4096 + 2048 + (row & 2047)) * 128 + (col & 127);
          if (z == 1) { kout[co] = v; kbf[co] = (bf16)v; }
          else        { vout[co] = v; }
        }
      }
    }
  }
}

// ---------------- V cache -> transposed bf16  [BH][128][4096] ----------------
__global__ __launch_bounds__(256) void build_vt(const float* __restrict__ vsrc, bf16* __restrict__ vtb) {
  __shared__ float tile[64][65];
  const int tid = threadIdx.x;
  const int bh = blockIdx.z;
  const int t0 = blockIdx.x * 64, d0 = blockIdx.y * 64;
  const float* src = vsrc + ((size_t)bh * LT + t0) * HD + d0;
#pragma unroll
  for (int i = 0; i < 4; i++) {
    int idx = i * 256 + tid;
    int rr = idx >> 4, c4 = (idx & 15) * 4;
    float4 v = *(const float4*)(src + rr * HD + c4);
    tile[rr][c4 + 0] = v.x; tile[rr][c4 + 1] = v.y; tile[rr][c4 + 2] = v.z; tile[rr][c4 + 3] = v.w;
  }
  __syncthreads();
  bf16* dst = vtb + (size_t)bh * HD * LT + (size_t)d0 * LT + t0;
#pragma unroll
  for (int i = 0; i < 4; i++) {
    int idx = i * 256 + tid;
    int dr = idx >> 4, c4 = (idx & 15) * 4;
    bf16x4 o = { (bf16)tile[c4 + 0][dr], (bf16)tile[c4 + 1][dr],
                 (bf16)tile[c4 + 2][dr], (bf16)tile[c4 + 3][dr] };
    *(bf16x4*)(dst + (size_t)dr * LT + c4) = o;
  }
}

// ---------------- flash attention: 8 waves x 16 q-rows, KVBLK=64 ----------------
// R2: double-buffered K/Vt LDS, STAGE(t+1) issued before compute(t) (T3 2-phase),
//     ONE barrier per K-tile (P-buffer is wave-private: in-wave lgkmcnt(0) only),
//     pbuf XOR-swizzled instead of padded -> LDS exactly 80 KiB = 2 blocks/CU.
__global__ __launch_bounds__(512) void attn(const bf16* __restrict__ qb, const bf16* __restrict__ kb,
                                            const bf16* __restrict__ vtb, bf16* __restrict__ ctxb) {
  __shared__ alignas(16) bf16 kbuf[2][64 * 128];    // [key][d], swizzled
  __shared__ alignas(16) bf16 vtbuf[2][128 * 64];   // [d][key], swizzled
  __shared__ alignas(16) bf16 pbuf[8][16 * 64];     // per-wave [q][key], swizzled
  const int tid = threadIdx.x, lane = tid & 63, w = tid >> 6;
  const int fr = lane & 15, fg = lane >> 4;
  const int bh = blockIdx.y, b = bh >> 4;
  const int q0 = blockIdx.x * 128;
  const bf16* qrow = qb + (size_t)(b * LQ + q0 + w * 16 + fr) * D_MODEL + (bh & 15) * HD;
  bf16x8 aq[4];
#pragma unroll
  for (int c = 0; c < 4; c++) aq[c] = *(const bf16x8*)(qrow + c * 32 + fg * 8);
  const bf16* Kb = kb + (size_t)bh * LT * HD;
  const bf16* Vt = vtb + (size_t)bh * HD * LT;
  float m_[4], s_[4];
  f32x4 ctx[8];
#pragma unroll
  for (int r = 0; r < 4; r++) { m_[r] = -__builtin_inff(); s_[r] = 0.f; }
#pragma unroll
  for (int d = 0; d < 8; d++) ctx[d] = (f32x4){0.f, 0.f, 0.f, 0.f};

  // staging geometry (inverse-swizzled global source col, linear LDS dest)
  const int krow_lo = w * 4 + (lane >> 4);                 // 0..31
  const int kscol = (((lane & 15) ^ (krow_lo & 7)) * 8);
  const int vr = w * 8 + (lane >> 3);                      // 0..63
  const int vscol = (((lane & 7) ^ (vr & 7)) * 8);

#define STAGE_KV(k0s, sel)                                                                  \
  do {                                                                                      \
    _Pragma("unroll")                                                                       \
    for (int j = 0; j < 2; j++) {                                                           \
      gload16(Kb + (size_t)((k0s) + j * 32 + krow_lo) * HD + kscol,                         \
              &kbuf[sel][(j * 32 + w * 4) * HD]);                                           \
      gload16(Vt + (size_t)(j * 64 + vr) * LT + (k0s) + vscol,                              \
              &vtbuf[sel][(j * 64 + w * 8) * 64]);                                          \
    }                                                                                       \
  } while (0)

  STAGE_KV(0, 0);
  int sel = 0;
  for (int k0 = 0; k0 < LT; k0 += 64) {
    __syncthreads();                       // buf[sel] staged; buf[sel^1] free
    const int kn = (k0 + 64) & (LT - 1);   // wrap on last iter (harmless re-stage)
    STAGE_KV(kn, sel ^ 1);                 // overlaps with the whole compute below
    const bf16* kcur = &kbuf[sel][0];
    const bf16* vcur = &vtbuf[sel][0];
    // S = Q * K^T (Q pre-scaled by 1/sqrt(128)*log2e): 4 col groups of 16 keys
    f32x4 sS[4];
#pragma unroll
    for (int n = 0; n < 4; n++) {
      sS[n] = (f32x4){0.f, 0.f, 0.f, 0.f};
#pragma unroll
      for (int c = 0; c < 4; c++) {
        bf16x8 kf = *(const bf16x8*)(kcur + (n * 16 + fr) * HD + (((c * 4 + fg) ^ (fr & 7)) * 8));
        sS[n] = __builtin_amdgcn_mfma_f32_16x16x32_bf16(aq[c], kf, sS[n], 0, 0, 0);
      }
    }
    // online softmax in log2 domain; row layout q = fg*4 + r
    float al[4], rs[4];
#pragma unroll
    for (int r = 0; r < 4; r++) {
      float t = fmaxf(fmaxf(sS[0][r], sS[1][r]), fmaxf(sS[2][r], sS[3][r]));
#pragma unroll
      for (int mk = 1; mk <= 8; mk <<= 1) t = fmaxf(t, __shfl_xor(t, mk));
      float mn = fmaxf(m_[r], t);
      al[r] = __builtin_amdgcn_exp2f(m_[r] - mn);
      m_[r] = mn;
      float rsum = 0.f;
#pragma unroll
      for (int n = 0; n < 4; n++) {
        float pe = __builtin_amdgcn_exp2f(sS[n][r] - mn);
        sS[n][r] = pe;
        rsum += pe;
      }
      rs[r] = rsum;
    }
#pragma unroll
    for (int r = 0; r < 4; r++) {
#pragma unroll
      for (int mk = 1; mk <= 8; mk <<= 1) rs[r] += __shfl_xor(rs[r], mk);
      s_[r] = s_[r] * al[r] + rs[r];
    }
#pragma unroll
    for (int d = 0; d < 8; d++)
#pragma unroll
      for (int r = 0; r < 4; r++) ctx[d][r] *= al[r];
    // P -> per-wave LDS (A-fragment layout), XOR-swizzled 16B granules
    bf16* pw = &pbuf[w][0];
#pragma unroll
    for (int n = 0; n < 4; n++) {
      const int gr = n * 2 + (fr >> 3);
#pragma unroll
      for (int r = 0; r < 4; r++) {
        const int row = fg * 4 + r;
        pw[row * 64 + ((gr ^ (row & 7)) * 8) + (fr & 7)] = (bf16)sS[n][r];
      }
    }
    // wave-private buffer: in-wave ordering only (DS ops complete in order)
    asm volatile("s_waitcnt lgkmcnt(0)" ::: "memory");
    bf16x8 pf0 = *(const bf16x8*)(pw + fr * 64 + ((fg ^ (fr & 7)) * 8));
    bf16x8 pf1 = *(const bf16x8*)(pw + fr * 64 + (((4 + fg) ^ (fr & 7)) * 8));
#pragma unroll
    for (int d = 0; d < 8; d++) {
      bf16x8 v0 = *(const bf16x8*)(vcur + (d * 16 + fr) * 64 + ((fg ^ (fr & 7)) * 8));
      ctx[d] = __builtin_amdgcn_mfma_f32_16x16x32_bf16(pf0, v0, ctx[d], 0, 0, 0);
      bf16x8 v1 = *(const bf16x8*)(vcur + (d * 16 + fr) * 64 + (((4 + fg) ^ (fr & 7)) * 8));
      ctx[d] = __builtin_amdgcn_mfma_f32_16x16x32_bf16(pf1, v1, ctx[d], 0, 0, 0);
    }
    sel ^= 1;
  }
#undef STAGE_KV
  float inv[4];
#pragma unroll
  for (int r = 0; r < 4; r++) inv[r] = 1.f / s_[r];
  bf16* crow = ctxb + (size_t)(b * LQ + q0 + w * 16 + fg * 4) * D_MODEL + (bh & 15) * HD + fr;
#pragma unroll
  for (int r = 0; r < 4; r++)
#pragma unroll
    for (int d = 0; d < 8; d++)
      crow[(size_t)r * D_MODEL + d * 16] = (bf16)(ctx[d][r] * inv[r]);
}

// ---------------- output projection ----------------
__global__ __launch_bounds__(256) void out_gemm(const bf16* __restrict__ cb, const bf16* __restrict__ wo,
                                                const float* __restrict__ bo, float* __restrict__ out) {
  __shared__ alignas(16) bf16 As[128 * 64];
  __shared__ alignas(16) bf16 Bs[128 * 64];
  f32x4 acc[4][4];
#pragma unroll
  for (int a = 0; a < 4; a++)
#pragma unroll
    for (int b = 0; b < 4; b++) acc[a][b] = (f32x4){0.f, 0.f, 0.f, 0.f};
  const int m0 = blockIdx.y * 128, n0 = blockIdx.x * 128;
  gemm128_mainloop(cb, wo, m0, n0, As, Bs, acc);
  const int lane = threadIdx.x & 63, w = threadIdx.x >> 6;
  const int wm = (w >> 1) * 64, wn = (w & 1) * 64, fr = lane & 15, fg = lane >> 4;
#pragma unroll
  for (int ni = 0; ni < 4; ni++) {
    int col = n0 + wn + ni * 16 + fr;
    float bi = bo[col];
#pragma unroll
    for (int mi = 0; mi < 4; mi++)
#pragma unroll
      for (int r = 0; r < 4; r++) {
        int row = m0 + wm + mi * 16 + fg * 4 + r;
        out[(size_t)row * 2048 + col] = acc[mi][ni][r] + bi;
      }
  }
}

extern "C" void kernel_launch(void* const* d_in, const int* in_sizes, int n_in,
                              void* d_out, int out_size, void* d_ws, size_t ws_size,
                              hipStream_t stream) {
  const float* x  = (const float*)d_in[0];
  const float* pk = (const float*)d_in[1];
  const float* pv = (const float*)d_in[2];
  const float* Wq = (const float*)d_in[3];
  const float* bq = (const float*)d_in[4];
  const float* Wk = (const float*)d_in[5];
  const float* bk = (const float*)d_in[6];
  const float* Wv = (const float*)d_in[7];
  const float* bv = (const float*)d_in[8];
  const float* Wo = (const float*)d_in[9];
  const float* bo = (const float*)d_in[10];

  float* out  = (float*)d_out;
  float* kout = out + 8388608;   // B*L*D
  float* vout = out + 25165824;

  char* p = (char*)d_ws;
  bf16* xb  = (bf16*)p;                   // 16 MiB, reused as ctxb after QKV gemm
  bf16* wb  = (bf16*)(p + 16777216);      // 32 MiB: Wq,Wk,Wv,Wo bf16
  bf16* qb  = (bf16*)(p + 50331648);      // 16 MiB (pre-scaled Q)
  bf16* kbf = (bf16*)(p + 67108864);      // 32 MiB K cache bf16 [BH][4096][128]
  bf16* vtb = (bf16*)(p + 100663296);     // 32 MiB V^T cache bf16 [BH][128][4096]
  bf16* ctxb = xb;

  conv_bf16<<<8192, 256, 0, stream>>>(x, xb, 8388608);
  conv_bf16<<<4096, 256, 0, stream>>>(Wq, wb,            4194304);
  conv_bf16<<<4096, 256, 0, stream>>>(Wk, wb + 4194304,  4194304);
  conv_bf16<<<4096, 256, 0, stream>>>(Wv, wb + 8388608,  4194304);
  conv_bf16<<<4096, 256, 0, stream>>>(Wo, wb + 12582912, 4194304);
  copy_past<<<8192, 256, 0, stream>>>(pk, kout, kbf);
  copy_past<<<8192, 256, 0, stream>>>(pv, vout, nullptr);

  qkv_gemm<<<dim3(16, 32, 3), 256, 0, stream>>>(xb, wb, bq, bk, bv, qb, kout, vout, kbf);
  build_vt<<<dim3(64, 2, 32), 256, 0, stream>>>(vout, vtb);
  attn<<<dim3(16, 32), 512, 0, stream>>>(qb, kbf, vtb, ctxb);
  out_gemm<<<dim3(16, 32), 256, 0, stream>>>(ctxb, wb + 12582912, bo, out);
}

// Round 4
// 550.461 us; speedup vs baseline: 1.5516x; 1.0868x over previous
//
#include <hip/hip_runtime.h>
#include <cstdint>
#include <cstddef>

typedef __bf16 bf16;
typedef __bf16 bf16x8 __attribute__((ext_vector_type(8)));
typedef __bf16 bf16x4 __attribute__((ext_vector_type(4)));
typedef float f32x4 __attribute__((ext_vector_type(4)));

#define D_MODEL 2048
#define NH 16
#define HD 128
#define LQ 2048
#define LT 4096

__device__ __forceinline__ void gload16(const void* g, void* l) {
  __builtin_amdgcn_global_load_lds((const __attribute__((address_space(1))) void*)g,
                                   (__attribute__((address_space(3))) void*)l, 16, 0, 0);
}

// ---------------- elementwise fp32 -> bf16 ----------------
__global__ __launch_bounds__(256) void conv_bf16(const float* __restrict__ s, bf16* __restrict__ d, int n) {
  int i = (blockIdx.x * 256 + threadIdx.x) * 4;
  if (i >= n) return;
  float4 v = *(const float4*)(s + i);
  bf16x4 o = { (bf16)v.x, (bf16)v.y, (bf16)v.z, (bf16)v.w };
  *(bf16x4*)(d + i) = o;
}

// ---------------- copy past K/V into cache (fp32 out, optional bf16) ----------------
// src layout [BH][2048][128]; dst layout [BH][4096][128] rows 0..2047
__global__ __launch_bounds__(256) void copy_past(const float* __restrict__ src, float* __restrict__ dstf,
                                                 bf16* __restrict__ dstb) {
  int i = (blockIdx.x * 256 + threadIdx.x) * 4;
  int bh = i >> 18;          // / (2048*128)
  int rem = i & 262143;
  size_t o = ((size_t)bh << 19) + rem;   // * (4096*128)
  float4 v = *(const float4*)(src + i);
  *(float4*)(dstf + o) = v;
  if (dstb) {
    bf16x4 ob = { (bf16)v.x, (bf16)v.y, (bf16)v.z, (bf16)v.w };
    *(bf16x4*)(dstb + o) = ob;
  }
}

// ---------------- shared 128x128 bf16 GEMM mainloop (C = A * B^T), K = 2048 ----------------
__device__ __forceinline__ void gemm128_mainloop(const bf16* __restrict__ A, const bf16* __restrict__ B,
                                                 int m0, int n0, bf16* As, bf16* Bs, f32x4 (&acc)[4][4]) {
  const int tid = threadIdx.x, lane = tid & 63, w = tid >> 6;
  const int srow = w * 8 + (lane >> 3), scol = (lane & 7) * 8;
  const int wm = (w >> 1) * 64, wn = (w & 1) * 64, fr = lane & 15, fg = lane >> 4;
  for (int k0 = 0; k0 < 2048; k0 += 64) {
#pragma unroll
    for (int i = 0; i < 4; i++) {
      gload16(A + (size_t)(m0 + i * 32 + srow) * 2048 + k0 + scol, As + (i * 32 + w * 8) * 64);
      gload16(B + (size_t)(n0 + i * 32 + srow) * 2048 + k0 + scol, Bs + (i * 32 + w * 8) * 64);
    }
    __syncthreads();
#pragma unroll
    for (int kk = 0; kk < 2; kk++) {
      bf16x8 af[4], bfr[4];
#pragma unroll
      for (int mi = 0; mi < 4; mi++) af[mi] = *(const bf16x8*)(As + (wm + mi * 16 + fr) * 64 + kk * 32 + fg * 8);
#pragma unroll
      for (int ni = 0; ni < 4; ni++) bfr[ni] = *(const bf16x8*)(Bs + (wn + ni * 16 + fr) * 64 + kk * 32 + fg * 8);
#pragma unroll
      for (int mi = 0; mi < 4; mi++)
#pragma unroll
        for (int ni = 0; ni < 4; ni++)
          acc[mi][ni] = __builtin_amdgcn_mfma_f32_16x16x32_bf16(af[mi], bfr[ni], acc[mi][ni], 0, 0, 0);
    }
    __syncthreads();
  }
}

// ---------------- QKV projection; z = 0:Q  1:K  2:V ----------------
__global__ __launch_bounds__(256) void qkv_gemm(const bf16* __restrict__ xb, const bf16* __restrict__ wb,
    const float* __restrict__ bq, const float* __restrict__ bk, const float* __restrict__ bv,
    bf16* __restrict__ qb, float* __restrict__ kout, float* __restrict__ vout, bf16* __restrict__ kbf) {
  __shared__ alignas(16) bf16 As[128 * 64];
  __shared__ alignas(16) bf16 Bs[128 * 64];
  f32x4 acc[4][4];
#pragma unroll
  for (int a = 0; a < 4; a++)
#pragma unroll
    for (int b = 0; b < 4; b++) acc[a][b] = (f32x4){0.f, 0.f, 0.f, 0.f};
  const int z = blockIdx.z;
  const int m0 = blockIdx.y * 128, n0 = blockIdx.x * 128;
  gemm128_mainloop(xb, wb + (size_t)z * 4194304, m0, n0, As, Bs, acc);
  const int lane = threadIdx.x & 63, w = threadIdx.x >> 6;
  const int wm = (w >> 1) * 64, wn = (w & 1) * 64, fr = lane & 15, fg = lane >> 4;
  const float* bias = (z == 0) ? bq : (z == 1 ? bk : bv);
#pragma unroll
  for (int ni = 0; ni < 4; ni++) {
    int col = n0 + wn + ni * 16 + fr;
    float bi = bias[col];
#pragma unroll
    for (int mi = 0; mi < 4; mi++) {
#pragma unroll
      for (int r = 0; r < 4; r++) {
        int row = m0 + wm + mi * 16 + fg * 4 + r;
        float v = acc[mi][ni][r] + bi;
        if (z == 0) {
          // fold 1/sqrt(128) * log2(e) so attn can use v_exp_f32 (exp2) directly
          qb[(size_t)row * 2048 + col] = (bf16)(v * 0.12751744955867606f);
        } else {
          size_t co = (((size_t)(row >> 11) * 16 + (col >> 7)) * 4096 + 2048 + (row & 2047)) * 128 + (col & 127);
          if (z == 1) { kout[co] = v; kbf[co] = (bf16)v; }
          else        { vout[co] = v; }
        }
      }
    }
  }
}

// ---------------- V cache -> transposed bf16  [BH][128][4096] ----------------
__global__ __launch_bounds__(256) void build_vt(const float* __restrict__ vsrc, bf16* __restrict__ vtb) {
  __shared__ float tile[64][65];
  const int tid = threadIdx.x;
  const int bh = blockIdx.z;
  const int t0 = blockIdx.x * 64, d0 = blockIdx.y * 64;
  const float* src = vsrc + ((size_t)bh * LT + t0) * HD + d0;
#pragma unroll
  for (int i = 0; i < 4; i++) {
    int idx = i * 256 + tid;
    int rr = idx >> 4, c4 = (idx & 15) * 4;
    float4 v = *(const float4*)(src + rr * HD + c4);
    tile[rr][c4 + 0] = v.x; tile[rr][c4 + 1] = v.y; tile[rr][c4 + 2] = v.z; tile[rr][c4 + 3] = v.w;
  }
  __syncthreads();
  bf16* dst = vtb + (size_t)bh * HD * LT + (size_t)d0 * LT + t0;
#pragma unroll
  for (int i = 0; i < 4; i++) {
    int idx = i * 256 + tid;
    int dr = idx >> 4, c4 = (idx & 15) * 4;
    bf16x4 o = { (bf16)tile[c4 + 0][dr], (bf16)tile[c4 + 1][dr],
                 (bf16)tile[c4 + 2][dr], (bf16)tile[c4 + 3][dr] };
    *(bf16x4*)(dst + (size_t)dr * LT + c4) = o;
  }
}

// ---------------- flash attention: 4 waves x 32 q-rows, KVBLK=64 ----------------
// R3: LDS-pipe-bound fix — each wave handles TWO 16-row q-sets so every K/V
//     fragment ds_read feeds 2 MFMAs (fragment traffic per MFMA halved);
//     softmax denominator via MFMA with all-ones B-frag (kills shfl-sum chain);
//     defer-max (T13, THR=8 in log2 domain) skips ctx rescale most iters.
//     LDS = 32K(K,dbuf) + 32K(Vt,dbuf) + 16K(P) = 80 KiB -> 2 blocks/CU.
__global__ __launch_bounds__(256, 2) void attn(const bf16* __restrict__ qb, const bf16* __restrict__ kb,
                                               const bf16* __restrict__ vtb, bf16* __restrict__ ctxb) {
  __shared__ alignas(16) bf16 kbuf[2][64 * 128];    // [key][d], swizzled
  __shared__ alignas(16) bf16 vtbuf[2][128 * 64];   // [d][key], swizzled
  __shared__ alignas(16) bf16 pbuf[4][2][16 * 64];  // per-wave, per-set [q][key], swizzled
  const int tid = threadIdx.x, lane = tid & 63, w = tid >> 6;   // w in 0..3
  const int fr = lane & 15, fg = lane >> 4;
  const int bh = blockIdx.y, b = bh >> 4;
  const int q0 = blockIdx.x * 128;
  // two 16-row q-sets per wave: rows q0 + w*32 + s*16 + {fr | fg*4+r}
  bf16x8 aq[2][4];
#pragma unroll
  for (int s = 0; s < 2; s++) {
    const bf16* qrow = qb + (size_t)(b * LQ + q0 + w * 32 + s * 16 + fr) * D_MODEL + (bh & 15) * HD;
#pragma unroll
    for (int c = 0; c < 4; c++) aq[s][c] = *(const bf16x8*)(qrow + c * 32 + fg * 8);
  }
  const bf16* Kb = kb + (size_t)bh * LT * HD;
  const bf16* Vt = vtb + (size_t)bh * HD * LT;
  float m_[2][4];
  f32x4 ctx[2][8], sum_[2];
#pragma unroll
  for (int s = 0; s < 2; s++) {
#pragma unroll
    for (int r = 0; r < 4; r++) m_[s][r] = -__builtin_inff();
#pragma unroll
    for (int d = 0; d < 8; d++) ctx[s][d] = (f32x4){0.f, 0.f, 0.f, 0.f};
    sum_[s] = (f32x4){0.f, 0.f, 0.f, 0.f};
  }
  bf16x8 vones;
#pragma unroll
  for (int j = 0; j < 8; j++) vones[j] = (bf16)1.0f;

  // staging: 256 threads, 4 rounds each for K (16 rows/round) and Vt (32 rows/round)
  // inverse-swizzled global source col, linear LDS dest (rule #21)
#define STAGE_KV(k0s, sel)                                                                   \
  do {                                                                                       \
    _Pragma("unroll")                                                                        \
    for (int j = 0; j < 4; j++) {                                                            \
      const int krow = j * 16 + w * 4 + (lane >> 4);                                         \
      const int kscol = ((lane & 15) ^ (krow & 7)) * 8;                                      \
      gload16(Kb + (size_t)((k0s) + krow) * HD + kscol, &kbuf[sel][(j * 16 + w * 4) * HD]);  \
      const int vrw = j * 32 + w * 8 + (lane >> 3);                                          \
      const int vscol = ((lane & 7) ^ (vrw & 7)) * 8;                                        \
      gload16(Vt + (size_t)vrw * LT + (k0s) + vscol, &vtbuf[sel][(j * 32 + w * 8) * 64]);    \
    }                                                                                        \
  } while (0)

  STAGE_KV(0, 0);
  int sel = 0;
  for (int k0 = 0; k0 < LT; k0 += 64) {
    __syncthreads();                       // buf[sel] staged; buf[sel^1] free
    const int kn = (k0 + 64) & (LT - 1);   // wrap on last iter (harmless re-stage)
    STAGE_KV(kn, sel ^ 1);                 // overlaps with the whole compute below
    const bf16* kcur = &kbuf[sel][0];
    const bf16* vcur = &vtbuf[sel][0];
    // S = Q K^T for both q-sets; each kf read feeds 2 MFMAs
    f32x4 sS[2][4];
#pragma unroll
    for (int n = 0; n < 4; n++) {
      sS[0][n] = (f32x4){0.f, 0.f, 0.f, 0.f};
      sS[1][n] = (f32x4){0.f, 0.f, 0.f, 0.f};
#pragma unroll
      for (int c = 0; c < 4; c++) {
        bf16x8 kf = *(const bf16x8*)(kcur + (n * 16 + fr) * HD + (((c * 4 + fg) ^ (fr & 7)) * 8));
        sS[0][n] = __builtin_amdgcn_mfma_f32_16x16x32_bf16(aq[0][c], kf, sS[0][n], 0, 0, 0);
        sS[1][n] = __builtin_amdgcn_mfma_f32_16x16x32_bf16(aq[1][c], kf, sS[1][n], 0, 0, 0);
      }
    }
    // tile max per row (row q = fg*4+r within set), 4-step shfl over fr group
    float tmax[2][4];
    int ok = 1;
#pragma unroll
    for (int s = 0; s < 2; s++)
#pragma unroll
      for (int r = 0; r < 4; r++) {
        float t = fmaxf(fmaxf(sS[s][0][r], sS[s][1][r]), fmaxf(sS[s][2][r], sS[s][3][r]));
#pragma unroll
        for (int mk = 1; mk <= 8; mk <<= 1) t = fmaxf(t, __shfl_xor(t, mk));
        tmax[s][r] = t;
        ok &= (t <= m_[s][r] + 8.f);
      }
    // defer-max: only rescale when some row's max grew past THR=8 (log2 units)
    if (!__all(ok)) {
#pragma unroll
      for (int s = 0; s < 2; s++)
#pragma unroll
        for (int r = 0; r < 4; r++) {
          float mn = fmaxf(m_[s][r], tmax[s][r]);
          float al = __builtin_amdgcn_exp2f(m_[s][r] - mn);
          m_[s][r] = mn;
#pragma unroll
          for (int d = 0; d < 8; d++) ctx[s][d][r] *= al;
          sum_[s][r] *= al;
        }
    }
    // P = exp2(S - m), write to per-wave LDS (A-frag layout, XOR-swizzled)
#pragma unroll
    for (int s = 0; s < 2; s++) {
      bf16* pw = &pbuf[w][s][0];
#pragma unroll
      for (int n = 0; n < 4; n++) {
        const int gr = n * 2 + (fr >> 3);
#pragma unroll
        for (int r = 0; r < 4; r++) {
          const int row = fg * 4 + r;
          pw[row * 64 + ((gr ^ (row & 7)) * 8) + (fr & 7)] =
              (bf16)__builtin_amdgcn_exp2f(sS[s][n][r] - m_[s][r]);
        }
      }
    }
    // wave-private buffer: in-wave ordering only
    asm volatile("s_waitcnt lgkmcnt(0)" ::: "memory");
    bf16x8 pf[2][2];
#pragma unroll
    for (int s = 0; s < 2; s++) {
      const bf16* pw = &pbuf[w][s][0];
      pf[s][0] = *(const bf16x8*)(pw + fr * 64 + ((fg ^ (fr & 7)) * 8));
      pf[s][1] = *(const bf16x8*)(pw + fr * 64 + (((4 + fg) ^ (fr & 7)) * 8));
    }
    // PV: each v fragment feeds both q-sets
#pragma unroll
    for (int d = 0; d < 8; d++) {
      bf16x8 v0 = *(const bf16x8*)(vcur + (d * 16 + fr) * 64 + ((fg ^ (fr & 7)) * 8));
      ctx[0][d] = __builtin_amdgcn_mfma_f32_16x16x32_bf16(pf[0][0], v0, ctx[0][d], 0, 0, 0);
      ctx[1][d] = __builtin_amdgcn_mfma_f32_16x16x32_bf16(pf[1][0], v0, ctx[1][d], 0, 0, 0);
      bf16x8 v1 = *(const bf16x8*)(vcur + (d * 16 + fr) * 64 + (((4 + fg) ^ (fr & 7)) * 8));
      ctx[0][d] = __builtin_amdgcn_mfma_f32_16x16x32_bf16(pf[0][1], v1, ctx[0][d], 0, 0, 0);
      ctx[1][d] = __builtin_amdgcn_mfma_f32_16x16x32_bf16(pf[1][1], v1, ctx[1][d], 0, 0, 0);
    }
    // denominator via MFMA against all-ones B: every output col = row-sum of P
#pragma unroll
    for (int s = 0; s < 2; s++) {
      sum_[s] = __builtin_amdgcn_mfma_f32_16x16x32_bf16(pf[s][0], vones, sum_[s], 0, 0, 0);
      sum_[s] = __builtin_amdgcn_mfma_f32_16x16x32_bf16(pf[s][1], vones, sum_[s], 0, 0, 0);
    }
    sel ^= 1;
  }
#undef STAGE_KV
#pragma unroll
  for (int s = 0; s < 2; s++) {
    float inv[4];
#pragma unroll
    for (int r = 0; r < 4; r++) inv[r] = 1.f / sum_[s][r];
    bf16* crow = ctxb + (size_t)(b * LQ + q0 + w * 32 + s * 16 + fg * 4) * D_MODEL + (bh & 15) * HD + fr;
#pragma unroll
    for (int r = 0; r < 4; r++)
#pragma unroll
      for (int d = 0; d < 8; d++)
        crow[(size_t)r * D_MODEL + d * 16] = (bf16)(ctx[s][d][r] * inv[r]);
  }
}

// ---------------- output projection ----------------
__global__ __launch_bounds__(256) void out_gemm(const bf16* __restrict__ cb, const bf16* __restrict__ wo,
                                                const float* __restrict__ bo, float* __restrict__ out) {
  __shared__ alignas(16) bf16 As[128 * 64];
  __shared__ alignas(16) bf16 Bs[128 * 64];
  f32x4 acc[4][4];
#pragma unroll
  for (int a = 0; a < 4; a++)
#pragma unroll
    for (int b = 0; b < 4; b++) acc[a][b] = (f32x4){0.f, 0.f, 0.f, 0.f};
  const int m0 = blockIdx.y * 128, n0 = blockIdx.x * 128;
  gemm128_mainloop(cb, wo, m0, n0, As, Bs, acc);
  const int lane = threadIdx.x & 63, w = threadIdx.x >> 6;
  const int wm = (w >> 1) * 64, wn = (w & 1) * 64, fr = lane & 15, fg = lane >> 4;
#pragma unroll
  for (int ni = 0; ni < 4; ni++) {
    int col = n0 + wn + ni * 16 + fr;
    float bi = bo[col];
#pragma unroll
    for (int mi = 0; mi < 4; mi++)
#pragma unroll
      for (int r = 0; r < 4; r++) {
        int row = m0 + wm + mi * 16 + fg * 4 + r;
        out[(size_t)row * 2048 + col] = acc[mi][ni][r] + bi;
      }
  }
}

extern "C" void kernel_launch(void* const* d_in, const int* in_sizes, int n_in,
                              void* d_out, int out_size, void* d_ws, size_t ws_size,
                              hipStream_t stream) {
  const float* x  = (const float*)d_in[0];
  const float* pk = (const float*)d_in[1];
  const float* pv = (const float*)d_in[2];
  const float* Wq = (const float*)d_in[3];
  const float* bq = (const float*)d_in[4];
  const float* Wk = (const float*)d_in[5];
  const float* bk = (const float*)d_in[6];
  const float* Wv = (const float*)d_in[7];
  const float* bv = (const float*)d_in[8];
  const float* Wo = (const float*)d_in[9];
  const float* bo = (const float*)d_in[10];

  float* out  = (float*)d_out;
  float* kout = out + 8388608;   // B*L*D
  float* vout = out + 25165824;

  char* p = (char*)d_ws;
  bf16* xb  = (bf16*)p;                   // 16 MiB, reused as ctxb after QKV gemm
  bf16* wb  = (bf16*)(p + 16777216);      // 32 MiB: Wq,Wk,Wv,Wo bf16
  bf16* qb  = (bf16*)(p + 50331648);      // 16 MiB (pre-scaled Q)
  bf16* kbf = (bf16*)(p + 67108864);      // 32 MiB K cache bf16 [BH][4096][128]
  bf16* vtb = (bf16*)(p + 100663296);     // 32 MiB V^T cache bf16 [BH][128][4096]
  bf16* ctxb = xb;

  conv_bf16<<<8192, 256, 0, stream>>>(x, xb, 8388608);
  conv_bf16<<<4096, 256, 0, stream>>>(Wq, wb,            4194304);
  conv_bf16<<<4096, 256, 0, stream>>>(Wk, wb + 4194304,  4194304);
  conv_bf16<<<4096, 256, 0, stream>>>(Wv, wb + 8388608,  4194304);
  conv_bf16<<<4096, 256, 0, stream>>>(Wo, wb + 12582912, 4194304);
  copy_past<<<8192, 256, 0, stream>>>(pk, kout, kbf);
  copy_past<<<8192, 256, 0, stream>>>(pv, vout, nullptr);

  qkv_gemm<<<dim3(16, 32, 3), 256, 0, stream>>>(xb, wb, bq, bk, bv, qb, kout, vout, kbf);
  build_vt<<<dim3(64, 2, 32), 256, 0, stream>>>(vout, vtb);
  attn<<<dim3(16, 32), 256, 0, stream>>>(qb, kbf, vtb, ctxb);
  out_gemm<<<dim3(16, 32), 256, 0, stream>>>(ctxb, wb + 12582912, bo, out);
}